// Round 7
// baseline (338.636 us; speedup 1.0000x reference)
//
#include <hip/hip_runtime.h>
#include <hip/hip_bf16.h>

#define B_  2
#define S_  2048
#define H_  24
#define DH_ 32
#define E_  768
#define SW_ (S_/32)   // mask words per row = 64

typedef __attribute__((ext_vector_type(8))) short short8;   // 8 x bf16 bits
typedef __attribute__((ext_vector_type(4))) float f32x4;

static __device__ __forceinline__ short bf16bits(float f) {
    __hip_bfloat16 h = __float2bfloat16(f);
    return *reinterpret_cast<short*>(&h);
}
static __device__ __forceinline__ float bf16tof(short s) {
    __hip_bfloat16 h = *reinterpret_cast<__hip_bfloat16*>(&s);
    return __bfloat162float(h);
}
// 4 floats -> 4 bf16 packed in 8B
static __device__ __forceinline__ short4 pack4(float a, float b, float c, float d) {
    union { __hip_bfloat162 h[2]; short4 s; } u;
    u.h[0] = __float22bfloat162_rn(make_float2(a, b));
    u.h[1] = __float22bfloat162_rn(make_float2(c, d));
    return u.s;
}
static __device__ __forceinline__ short8 pack8f(const float* a, const float* b) {
    union { __hip_bfloat162 h[4]; short8 s; } u;
    u.h[0] = __float22bfloat162_rn(make_float2(a[0], a[1]));
    u.h[1] = __float22bfloat162_rn(make_float2(a[2], a[3]));
    u.h[2] = __float22bfloat162_rn(make_float2(b[0], b[1]));
    u.h[3] = __float22bfloat162_rn(make_float2(b[2], b[3]));
    return u.s;
}
static __device__ __forceinline__ short8 pack8(float4 a, float4 b) {
    union { __hip_bfloat162 h[4]; short8 s; } u;
    u.h[0] = __float22bfloat162_rn(make_float2(a.x, a.y));
    u.h[1] = __float22bfloat162_rn(make_float2(a.z, a.w));
    u.h[2] = __float22bfloat162_rn(make_float2(b.x, b.y));
    u.h[3] = __float22bfloat162_rn(make_float2(b.z, b.w));
    return u.s;
}

// Q pre-scaled by (1/sqrt(32))*log2(e): MFMA scores land in the exp2 domain.
// Masked branch substitutes -1e-6*log2(e).
#define QSCALE  0.25503487f
#define MLOG2E -1.4426950e-6f

// ---------------------------------------------------------------------------
// Kernel 0a: pack int32 mask -> bitmask via wave ballot.
// ---------------------------------------------------------------------------
__global__ __launch_bounds__(256) void maskpack_kernel(
    const int* __restrict__ mask, unsigned int* __restrict__ mbits)
{
    const int idx  = blockIdx.x * 256 + threadIdx.x;
    const int lane = threadIdx.x & 63;
    const unsigned long long bal = __ballot(mask[idx] != 0);
    if (lane == 0) {
        uint2 w;
        w.x = (unsigned int)(bal & 0xffffffffull);
        w.y = (unsigned int)(bal >> 32);
        *reinterpret_cast<uint2*>(mbits + (idx >> 5)) = w;   // idx 64-aligned
    }
}

// ---------------------------------------------------------------------------
// Kernel 0b: Wo fp32 -> bf16 (one-time)
// ---------------------------------------------------------------------------
__global__ __launch_bounds__(256) void woconv_kernel(
    const float* __restrict__ Wo, __hip_bfloat16* __restrict__ Wob)
{
    const int i = (blockIdx.x * 256 + threadIdx.x) * 4;
    const float4 w = *reinterpret_cast<const float4*>(Wo + i);
    *reinterpret_cast<short4*>(Wob + i) = pack4(w.x, w.y, w.z, w.w);
}

// ---------------------------------------------------------------------------
// Kernel 0c: QKV weights fp32 [h][d][e] -> bf16 transposed [h][e][d].
// ---------------------------------------------------------------------------
__global__ __launch_bounds__(256) void wtprep_kernel(
    const float* __restrict__ Wq, const float* __restrict__ Wk,
    const float* __restrict__ Wv,
    __hip_bfloat16* __restrict__ WTq, __hip_bfloat16* __restrict__ WTk,
    __hip_bfloat16* __restrict__ WTv)
{
    const int h = blockIdx.x;
    const int base = h * DH_ * DH_;
    for (int i = threadIdx.x; i < DH_ * DH_; i += 256) {
        const int d = i >> 5, e = i & 31;
        WTq[base + e * 32 + d] = __float2bfloat16(Wq[base + i]);
        WTk[base + e * 32 + d] = __float2bfloat16(Wk[base + i]);
        WTv[base + e * 32 + d] = __float2bfloat16(Wv[base + i]);
    }
}

// ---------------------------------------------------------------------------
// Kernel 1: MFMA QKV projection (16 s-rows/wave, 6 MFMAs).
// K is stored PERMUTED within each 32-key tile: key k=8q+4u+i goes to slot
// (u<<4)|(q*4+i) so attn's two score MFMAs produce P directly in PV
// B-operand register layout (reg j of [s0;s1] = key quad*8+j).
// grid = (S/64, B*H), block = 256.
// ---------------------------------------------------------------------------
__global__ __launch_bounds__(256) void qkv_kernel(
    const float* __restrict__ x,
    const __hip_bfloat16* __restrict__ WTq,
    const __hip_bfloat16* __restrict__ WTk,
    const __hip_bfloat16* __restrict__ WTv,
    __hip_bfloat16* __restrict__ Qo,
    __hip_bfloat16* __restrict__ Ko,      // permuted-key layout
    __hip_bfloat16* __restrict__ Vto)
{
    const int bh   = blockIdx.y;
    const int b    = bh / H_;
    const int h    = bh - b * H_;
    const int wave = threadIdx.x >> 6;
    const int lane = threadIdx.x & 63;
    const int col  = lane & 15;
    const int quad = lane >> 4;
    const int sw   = blockIdx.x * 64 + wave * 16;
    const int s    = sw + col;

    const float* xp = x + ((size_t)b * S_ + s) * E_ + h * DH_ + quad * 8;
    const float4 xa = *reinterpret_cast<const float4*>(xp);
    const float4 xb = *reinterpret_cast<const float4*>(xp + 4);
    const short8 xf = pack8(xa, xb);

    const int wofs = h * DH_ * DH_ + col * 32 + quad * 8;
    const short8 aQ0 = *reinterpret_cast<const short8*>(WTq + wofs);
    const short8 aQ1 = *reinterpret_cast<const short8*>(WTq + wofs + 16 * 32);
    const short8 aK0 = *reinterpret_cast<const short8*>(WTk + wofs);
    const short8 aK1 = *reinterpret_cast<const short8*>(WTk + wofs + 16 * 32);
    const short8 bV0 = *reinterpret_cast<const short8*>(WTv + wofs);
    const short8 bV1 = *reinterpret_cast<const short8*>(WTv + wofs + 16 * 32);

    const f32x4 z = {0.f, 0.f, 0.f, 0.f};
    const f32x4 qt0 = __builtin_amdgcn_mfma_f32_16x16x32_bf16(aQ0, xf, z, 0, 0, 0);
    const f32x4 qt1 = __builtin_amdgcn_mfma_f32_16x16x32_bf16(aQ1, xf, z, 0, 0, 0);
    const f32x4 kt0 = __builtin_amdgcn_mfma_f32_16x16x32_bf16(aK0, xf, z, 0, 0, 0);
    const f32x4 kt1 = __builtin_amdgcn_mfma_f32_16x16x32_bf16(aK1, xf, z, 0, 0, 0);
    const f32x4 vv0 = __builtin_amdgcn_mfma_f32_16x16x32_bf16(xf, bV0, z, 0, 0, 0);
    const f32x4 vv1 = __builtin_amdgcn_mfma_f32_16x16x32_bf16(xf, bV1, z, 0, 0, 0);

    __hip_bfloat16* qrow = Qo + ((size_t)bh * S_ + s) * DH_;
    *reinterpret_cast<short4*>(qrow + quad * 4) =
        pack4(qt0[0] * QSCALE, qt0[1] * QSCALE, qt0[2] * QSCALE, qt0[3] * QSCALE);
    *reinterpret_cast<short4*>(qrow + 16 + quad * 4) =
        pack4(qt1[0] * QSCALE, qt1[1] * QSCALE, qt1[2] * QSCALE, qt1[3] * QSCALE);

    const int t32  = s & 31;
    const int slot = (s & ~31) | (((t32 >> 2) & 1) << 4)
                   | (((t32 >> 3) << 2) | (t32 & 3));
    __hip_bfloat16* krow = Ko + ((size_t)bh * S_ + slot) * DH_;
    *reinterpret_cast<short4*>(krow + quad * 4)      = pack4(kt0[0], kt0[1], kt0[2], kt0[3]);
    *reinterpret_cast<short4*>(krow + 16 + quad * 4) = pack4(kt1[0], kt1[1], kt1[2], kt1[3]);

    const int sb = sw + quad * 4;
    *reinterpret_cast<short4*>(Vto + ((size_t)bh * DH_ + col) * S_ + sb) =
        pack4(vv0[0], vv0[1], vv0[2], vv0[3]);
    *reinterpret_cast<short4*>(Vto + ((size_t)bh * DH_ + 16 + col) * S_ + sb) =
        pack4(vv1[0], vv1[1], vv1[2], vv1[3]);
}

// ---------------------------------------------------------------------------
// Kernel 2: fused attention v6 — register P + EXPLICIT DEPTH-1 PREFETCH.
// R6 diagnosis: load->use distance 0 meant every wave ate full L2 latency
// every iter (all pipes <30% busy, 1150 cyc/iter vs ~350 of work). Here
// tile i+1's K/V/mask loads are issued before tile i's compute, so the
// vmcnt wait lands one full iteration after issue.
// NOTE: the final iteration prefetches one tile past the part end; those
// addresses land in the adjacent ws buffers (K->Vt, V->att, mbits->Wob) —
// valid memory, values never used.
// grid = (S/64, B*H, parts), block = 256 (4 waves x 16 q-rows)
// ---------------------------------------------------------------------------
__global__ __launch_bounds__(256) void attn_kernel(
    const __hip_bfloat16* __restrict__ Q,     // [B*H][S][DH] (pre-scaled)
    const __hip_bfloat16* __restrict__ K,     // [B*H][S][DH] permuted tiles
    const __hip_bfloat16* __restrict__ Vt,    // [B*H][DH][S]
    const unsigned int* __restrict__ mbits,   // [B][S][S/32]
    __hip_bfloat16* __restrict__ Opart,       // [parts][B][S][E] unnormalized
    float* __restrict__ lpart)                // [parts][B*H][S]
{
    const int bh   = blockIdx.y;
    const int b    = bh / H_;
    const int h    = bh - b * H_;
    const int part = blockIdx.z;
    const int nkey = S_ / gridDim.z;
    const int kbeg = part * nkey;
    const int wave = threadIdx.x >> 6;
    const int lane = threadIdx.x & 63;
    const int col  = lane & 15;
    const int quad = lane >> 4;
    const int q0   = blockIdx.x * 64 + wave * 16;

    const __hip_bfloat16* Qbh = Q  + (size_t)bh * S_ * DH_;
    const __hip_bfloat16* Kbh = K  + (size_t)bh * S_ * DH_;
    const __hip_bfloat16* Vbh = Vt + (size_t)bh * DH_ * S_;

    const short8 qfrag =
        *reinterpret_cast<const short8*>(Qbh + (size_t)(q0 + col) * DH_ + quad * 8);

    const __hip_bfloat16* Kp  = Kbh + (size_t)(kbeg + col) * DH_ + quad * 8;
    const __hip_bfloat16* Vp0 = Vbh + (size_t)col * S_ + kbeg + quad * 8;
    const __hip_bfloat16* Vp1 = Vbh + (size_t)(16 + col) * S_ + kbeg + quad * 8;
    const unsigned int*   mp  = mbits + (size_t)b * S_ * SW_
                              + (size_t)(q0 + col) * SW_ + (kbeg >> 5);

    f32x4 o0 = {0.f,0.f,0.f,0.f};   // O[q=col][d=quad*4+r]
    f32x4 o1 = {0.f,0.f,0.f,0.f};   // O[q=col][d=16+quad*4+r]
    float lsum = 0.f;

    // ---- prefetch tile 0 ----
    unsigned int mw_n = *mp;
    short8 kf0_n = *reinterpret_cast<const short8*>(Kp);
    short8 kf1_n = *reinterpret_cast<const short8*>(Kp + 16 * DH_);
    short8 vf0_n = *reinterpret_cast<const short8*>(Vp0);
    short8 vf1_n = *reinterpret_cast<const short8*>(Vp1);

    const int niter = nkey >> 5;
    for (int it = 0; it < niter; ++it) {
        // consume prefetched tile
        const unsigned int mw = mw_n;
        const short8 kf0 = kf0_n, kf1 = kf1_n;
        const short8 vf0 = vf0_n, vf1 = vf1_n;

        // issue next tile's loads NOW (unconditional; last-iter overread is
        // into adjacent ws buffers — see kernel comment)
        Kp  += 32 * DH_;
        Vp0 += 32;
        Vp1 += 32;
        mp  += 1;
        mw_n  = *mp;
        kf0_n = *reinterpret_cast<const short8*>(Kp);
        kf1_n = *reinterpret_cast<const short8*>(Kp + 16 * DH_);
        vf0_n = *reinterpret_cast<const short8*>(Vp0);
        vf1_n = *reinterpret_cast<const short8*>(Vp1);

        const f32x4 z = {0.f, 0.f, 0.f, 0.f};
        const f32x4 s0 = __builtin_amdgcn_mfma_f32_16x16x32_bf16(kf0, qfrag, z, 0, 0, 0);
        const f32x4 s1 = __builtin_amdgcn_mfma_f32_16x16x32_bf16(kf1, qfrag, z, 0, 0, 0);

        float p0[4], p1[4];
#pragma unroll
        for (int r = 0; r < 4; ++r) {
            const int kb = quad * 8 + r;
            const float t0 = ((mw >> kb)       & 1u) ? s0[r] : MLOG2E;  // key kb
            const float t1 = ((mw >> (kb + 4)) & 1u) ? s1[r] : MLOG2E;  // key kb+4
            p0[r] = __builtin_amdgcn_exp2f(t0);
            p1[r] = __builtin_amdgcn_exp2f(t1);
        }
        lsum += ((p0[0] + p0[1]) + (p0[2] + p0[3]))
              + ((p1[0] + p1[1]) + (p1[2] + p1[3]));

        // PV B-operand directly from registers: reg j = key quad*8+j
        const short8 pfrag = pack8f(p0, p1);

        o0 = __builtin_amdgcn_mfma_f32_16x16x32_bf16(vf0, pfrag, o0, 0, 0, 0);
        o1 = __builtin_amdgcn_mfma_f32_16x16x32_bf16(vf1, pfrag, o1, 0, 0, 0);
    }

    // reduce l across quads (lanes col, col+16, col+32, col+48)
    lsum += __shfl_xor(lsum, 16);
    lsum += __shfl_xor(lsum, 32);

    __hip_bfloat16* orow = Opart + (size_t)part * B_ * S_ * E_
                         + ((size_t)b * S_ + q0 + col) * E_ + h * DH_;
    *reinterpret_cast<short4*>(orow + quad * 4)      = pack4(o0[0], o0[1], o0[2], o0[3]);
    *reinterpret_cast<short4*>(orow + 16 + quad * 4) = pack4(o1[0], o1[1], o1[2], o1[3]);
    if (quad == 0)
        lpart[((size_t)part * B_ * H_ + bh) * S_ + q0 + col] = lsum;
}

// ---------------------------------------------------------------------------
// Kernel 2b: combine split-K partials: att = (sum_p O_p) / (sum_p l_p), bf16.
// In-place safe when Opart aliases att (parts==1).
// ---------------------------------------------------------------------------
__global__ __launch_bounds__(256) void combine_kernel(
    const __hip_bfloat16* __restrict__ Opart,
    const float* __restrict__ lpart,
    __hip_bfloat16* __restrict__ att,
    int parts)
{
    const size_t idx4 = ((size_t)blockIdx.x * 256 + threadIdx.x) * 4;
    const int e  = (int)(idx4 % E_);
    const size_t bs = idx4 / E_;
    const int h  = e >> 5;
    const int b  = (int)(bs / S_);
    const int s  = (int)(bs % S_);

    float a0 = 0.f, a1 = 0.f, a2 = 0.f, a3 = 0.f, l = 0.f;
    for (int p = 0; p < parts; ++p) {
        const short4 ov = *reinterpret_cast<const short4*>(
            Opart + (size_t)p * B_ * S_ * E_ + idx4);
        a0 += bf16tof(ov.x); a1 += bf16tof(ov.y);
        a2 += bf16tof(ov.z); a3 += bf16tof(ov.w);
        l += lpart[((size_t)p * B_ * H_ + b * H_ + h) * S_ + s];
    }
    const float linv = 1.0f / l;
    *reinterpret_cast<short4*>(att + idx4) =
        pack4(a0 * linv, a1 * linv, a2 * linv, a3 * linv);
}

// ---------------------------------------------------------------------------
// Kernel 3: output projection with depth-1 register prefetch (same latency
// medicine as attn: 5 loads/k-iter previously used immediately).
// Wave: 16 m x 64 n. grid = (M/16, 768/256), block = 256.
// Final-iter prefetch overreads one 32-col tile past row end -> lands in
// the next ws buffer region (valid memory, unused).
// ---------------------------------------------------------------------------
__global__ __launch_bounds__(256) void proj_kernel(
    const __hip_bfloat16* __restrict__ A,     // [4096][768] bf16 (ws)
    const __hip_bfloat16* __restrict__ Wob,   // [768][768] bf16 (ws)
    const float* __restrict__ bo,             // [768] fp32
    float* __restrict__ out)                  // [4096][768] fp32
{
    const int wave = threadIdx.x >> 6;
    const int lane = threadIdx.x & 63;
    const int col  = lane & 15;
    const int quad = lane >> 4;
    const int m0   = blockIdx.x * 16;
    const int n0   = blockIdx.y * 256 + wave * 64;

    const __hip_bfloat16* Ap = A   + (size_t)(m0 + col) * E_ + quad * 8;
    const __hip_bfloat16* Bp = Wob + (size_t)(n0 + col) * E_ + quad * 8;

    short8 af_n = *reinterpret_cast<const short8*>(Ap);
    short8 bf_n[4];
#pragma unroll
    for (int j = 0; j < 4; ++j)
        bf_n[j] = *reinterpret_cast<const short8*>(Bp + (size_t)j * 16 * E_);

    f32x4 acc[4] = {{0.f,0.f,0.f,0.f},{0.f,0.f,0.f,0.f},
                    {0.f,0.f,0.f,0.f},{0.f,0.f,0.f,0.f}};
    for (int k0 = 0; k0 < E_; k0 += 32) {
        const short8 af = af_n;
        short8 bf[4];
#pragma unroll
        for (int j = 0; j < 4; ++j) bf[j] = bf_n[j];

        Ap += 32; Bp += 32;
        af_n = *reinterpret_cast<const short8*>(Ap);
#pragma unroll
        for (int j = 0; j < 4; ++j)
            bf_n[j] = *reinterpret_cast<const short8*>(Bp + (size_t)j * 16 * E_);

#pragma unroll
        for (int j = 0; j < 4; ++j)
            acc[j] = __builtin_amdgcn_mfma_f32_16x16x32_bf16(af, bf[j], acc[j], 0, 0, 0);
    }
#pragma unroll
    for (int j = 0; j < 4; ++j) {
        const int n = n0 + j * 16 + col;
        const float bias = bo[n];
#pragma unroll
        for (int r = 0; r < 4; ++r) {
            const int m = m0 + quad * 4 + r;
            out[(size_t)m * E_ + n] = acc[j][r] + bias;
        }
    }
}

// ---------------------------------------------------------------------------
extern "C" void kernel_launch(void* const* d_in, const int* in_sizes, int n_in,
                              void* d_out, int out_size, void* d_ws, size_t ws_size,
                              hipStream_t stream)
{
    const float* emb = (const float*)d_in[0];
    const int*   msk = (const int*)d_in[1];
    const float* Wq  = (const float*)d_in[2];
    const float* Wk  = (const float*)d_in[3];
    const float* Wv  = (const float*)d_in[4];
    const float* Wo  = (const float*)d_in[5];
    const float* bo  = (const float*)d_in[6];
    float* out = (float*)d_out;

    const size_t nqkv = (size_t)B_ * H_ * S_ * DH_;   // 3,145,728 (= B*S*E)
    char* p = (char*)d_ws;
    __hip_bfloat16* Q    = (__hip_bfloat16*)p;  p += nqkv * 2;
    __hip_bfloat16* Kp   = (__hip_bfloat16*)p;  p += nqkv * 2;
    __hip_bfloat16* Vt   = (__hip_bfloat16*)p;  p += nqkv * 2;
    __hip_bfloat16* att  = (__hip_bfloat16*)p;  p += nqkv * 2;
    unsigned int*  mbits = (unsigned int*)p;    p += (size_t)B_ * S_ * SW_ * 4;
    __hip_bfloat16* Wob  = (__hip_bfloat16*)p;  p += (size_t)E_ * E_ * 2;
    __hip_bfloat16* WTq  = (__hip_bfloat16*)p;  p += (size_t)H_ * DH_ * DH_ * 2;
    __hip_bfloat16* WTk  = (__hip_bfloat16*)p;  p += (size_t)H_ * DH_ * DH_ * 2;
    __hip_bfloat16* WTv  = (__hip_bfloat16*)p;  p += (size_t)H_ * DH_ * DH_ * 2;
    const size_t base = (size_t)(p - (char*)d_ws);

    __hip_bfloat16* Opart = (__hip_bfloat16*)p;
    float* lpart;
    int parts = 1;
    const size_t slack = 4096;   // one-tile prefetch overread headroom
    const size_t need2 = base + (size_t)2 * nqkv * 2 + (size_t)2 * B_ * H_ * S_ * 4 + slack;
    if (ws_size >= need2) parts = 2;
    if (parts > 1) {
        lpart = (float*)(p + (size_t)parts * nqkv * 2);
    } else {
        Opart = att;                 // write unnormalized into att;
        lpart = (float*)p;           // combine normalizes in-place
    }

    maskpack_kernel<<<(B_ * S_ * S_) / 256, 256, 0, stream>>>(msk, mbits);
    woconv_kernel  <<<(E_ * E_) / 1024,     256, 0, stream>>>(Wo, Wob);
    wtprep_kernel  <<<H_,                   256, 0, stream>>>(Wq, Wk, Wv, WTq, WTk, WTv);
    qkv_kernel <<<dim3(S_ / 64, B_ * H_), 256, 0, stream>>>(emb, WTq, WTk, WTv, Q, Kp, Vt);
    attn_kernel<<<dim3(S_ / 64, B_ * H_, parts), 256, 0, stream>>>(Q, Kp, Vt, mbits, Opart, lpart);
    combine_kernel<<<(B_ * S_ * E_) / 1024, 256, 0, stream>>>(Opart, lpart, att, parts);
    proj_kernel<<<dim3((B_ * S_) / 16, E_ / 256), 256, 0, stream>>>(att, Wob, bo, out);
}

// Round 8
// 273.060 us; speedup vs baseline: 1.2402x; 1.2402x over previous
//
#include <hip/hip_runtime.h>
#include <hip/hip_bf16.h>

#define B_  2
#define S_  2048
#define H_  24
#define DH_ 32
#define E_  768
#define SW_ (S_/32)   // mask words per row = 64

#define NB_MASK ((B_*S_*S_)/256)   // 32768 blocks
#define NB_WO   ((E_*E_)/1024)     // 576 blocks
#define NB_WT   (H_)               // 24 blocks

typedef __attribute__((ext_vector_type(8))) short short8;   // 8 x bf16 bits
typedef __attribute__((ext_vector_type(4))) float f32x4;

static __device__ __forceinline__ float bf16tof(short s) {
    unsigned u = ((unsigned)(unsigned short)s) << 16;
    return __builtin_bit_cast(float, u);
}
// 4 floats -> 4 bf16 packed in 8B
static __device__ __forceinline__ short4 pack4(float a, float b, float c, float d) {
    union { __hip_bfloat162 h[2]; short4 s; } u;
    u.h[0] = __float22bfloat162_rn(make_float2(a, b));
    u.h[1] = __float22bfloat162_rn(make_float2(c, d));
    return u.s;
}
static __device__ __forceinline__ short8 pack8f(const float* a, const float* b) {
    union { __hip_bfloat162 h[4]; short8 s; } u;
    u.h[0] = __float22bfloat162_rn(make_float2(a[0], a[1]));
    u.h[1] = __float22bfloat162_rn(make_float2(a[2], a[3]));
    u.h[2] = __float22bfloat162_rn(make_float2(b[0], b[1]));
    u.h[3] = __float22bfloat162_rn(make_float2(b[2], b[3]));
    return u.s;
}
static __device__ __forceinline__ short8 pack8(float4 a, float4 b) {
    union { __hip_bfloat162 h[4]; short8 s; } u;
    u.h[0] = __float22bfloat162_rn(make_float2(a.x, a.y));
    u.h[1] = __float22bfloat162_rn(make_float2(a.z, a.w));
    u.h[2] = __float22bfloat162_rn(make_float2(b.x, b.y));
    u.h[3] = __float22bfloat162_rn(make_float2(b.z, b.w));
    return u.s;
}

// Q pre-scaled by (1/sqrt(32))*log2(e): MFMA scores land in the exp2 domain.
// Masked branch substitutes -1e-6*log2(e).
#define QSCALE  0.25503487f
#define MLOG2E -1.4426950e-6f

// ---------------------------------------------------------------------------
// Kernel 0: fused prep — maskpack + Wo->bf16 + QKV-weight transpose.
// Branch on blockIdx.x (wave-uniform). Saves 2 kernel launches.
// ---------------------------------------------------------------------------
__global__ __launch_bounds__(256) void prep_kernel(
    const int* __restrict__ mask, const float* __restrict__ Wo,
    const float* __restrict__ Wq, const float* __restrict__ Wk,
    const float* __restrict__ Wv,
    unsigned int* __restrict__ mbits, __hip_bfloat16* __restrict__ Wob,
    __hip_bfloat16* __restrict__ WTq, __hip_bfloat16* __restrict__ WTk,
    __hip_bfloat16* __restrict__ WTv)
{
    const int bx = blockIdx.x;
    if (bx < NB_MASK) {
        const int idx  = bx * 256 + threadIdx.x;
        const int lane = threadIdx.x & 63;
        const unsigned long long bal = __ballot(mask[idx] != 0);
        if (lane == 0) {
            uint2 w;
            w.x = (unsigned int)(bal & 0xffffffffull);
            w.y = (unsigned int)(bal >> 32);
            *reinterpret_cast<uint2*>(mbits + (idx >> 5)) = w;
        }
    } else if (bx < NB_MASK + NB_WO) {
        const int i = ((bx - NB_MASK) * 256 + threadIdx.x) * 4;
        const float4 w = *reinterpret_cast<const float4*>(Wo + i);
        *reinterpret_cast<short4*>(Wob + i) = pack4(w.x, w.y, w.z, w.w);
    } else {
        const int h = bx - NB_MASK - NB_WO;
        const int base = h * DH_ * DH_;
        for (int i = threadIdx.x; i < DH_ * DH_; i += 256) {
            const int d = i >> 5, e = i & 31;
            WTq[base + e * 32 + d] = __float2bfloat16(Wq[base + i]);
            WTk[base + e * 32 + d] = __float2bfloat16(Wk[base + i]);
            WTv[base + e * 32 + d] = __float2bfloat16(Wv[base + i]);
        }
    }
}

// ---------------------------------------------------------------------------
// Kernel 1: MFMA QKV projection (16 s-rows/wave, 6 MFMAs).
// K stored PERMUTED within each 32-key tile: key k=8q+4u+i -> slot
// (u<<4)|(q*4+i), so attn's score MFMAs produce P directly in PV B-operand
// register layout. grid = (S/64, B*H), block = 256.
// ---------------------------------------------------------------------------
__global__ __launch_bounds__(256) void qkv_kernel(
    const float* __restrict__ x,
    const __hip_bfloat16* __restrict__ WTq,
    const __hip_bfloat16* __restrict__ WTk,
    const __hip_bfloat16* __restrict__ WTv,
    __hip_bfloat16* __restrict__ Qo,
    __hip_bfloat16* __restrict__ Ko,      // permuted-key layout
    __hip_bfloat16* __restrict__ Vto)
{
    const int bh   = blockIdx.y;
    const int b    = bh / H_;
    const int h    = bh - b * H_;
    const int wave = threadIdx.x >> 6;
    const int lane = threadIdx.x & 63;
    const int col  = lane & 15;
    const int quad = lane >> 4;
    const int sw   = blockIdx.x * 64 + wave * 16;
    const int s    = sw + col;

    const float* xp = x + ((size_t)b * S_ + s) * E_ + h * DH_ + quad * 8;
    const float4 xa = *reinterpret_cast<const float4*>(xp);
    const float4 xb = *reinterpret_cast<const float4*>(xp + 4);
    const short8 xf = pack8(xa, xb);

    const int wofs = h * DH_ * DH_ + col * 32 + quad * 8;
    const short8 aQ0 = *reinterpret_cast<const short8*>(WTq + wofs);
    const short8 aQ1 = *reinterpret_cast<const short8*>(WTq + wofs + 16 * 32);
    const short8 aK0 = *reinterpret_cast<const short8*>(WTk + wofs);
    const short8 aK1 = *reinterpret_cast<const short8*>(WTk + wofs + 16 * 32);
    const short8 bV0 = *reinterpret_cast<const short8*>(WTv + wofs);
    const short8 bV1 = *reinterpret_cast<const short8*>(WTv + wofs + 16 * 32);

    const f32x4 z = {0.f, 0.f, 0.f, 0.f};
    const f32x4 qt0 = __builtin_amdgcn_mfma_f32_16x16x32_bf16(aQ0, xf, z, 0, 0, 0);
    const f32x4 qt1 = __builtin_amdgcn_mfma_f32_16x16x32_bf16(aQ1, xf, z, 0, 0, 0);
    const f32x4 kt0 = __builtin_amdgcn_mfma_f32_16x16x32_bf16(aK0, xf, z, 0, 0, 0);
    const f32x4 kt1 = __builtin_amdgcn_mfma_f32_16x16x32_bf16(aK1, xf, z, 0, 0, 0);
    const f32x4 vv0 = __builtin_amdgcn_mfma_f32_16x16x32_bf16(xf, bV0, z, 0, 0, 0);
    const f32x4 vv1 = __builtin_amdgcn_mfma_f32_16x16x32_bf16(xf, bV1, z, 0, 0, 0);

    __hip_bfloat16* qrow = Qo + ((size_t)bh * S_ + s) * DH_;
    *reinterpret_cast<short4*>(qrow + quad * 4) =
        pack4(qt0[0] * QSCALE, qt0[1] * QSCALE, qt0[2] * QSCALE, qt0[3] * QSCALE);
    *reinterpret_cast<short4*>(qrow + 16 + quad * 4) =
        pack4(qt1[0] * QSCALE, qt1[1] * QSCALE, qt1[2] * QSCALE, qt1[3] * QSCALE);

    const int t32  = s & 31;
    const int slot = (s & ~31) | (((t32 >> 2) & 1) << 4)
                   | (((t32 >> 3) << 2) | (t32 & 3));
    __hip_bfloat16* krow = Ko + ((size_t)bh * S_ + slot) * DH_;
    *reinterpret_cast<short4*>(krow + quad * 4)      = pack4(kt0[0], kt0[1], kt0[2], kt0[3]);
    *reinterpret_cast<short4*>(krow + 16 + quad * 4) = pack4(kt1[0], kt1[1], kt1[2], kt1[3]);

    const int sb = sw + quad * 4;
    *reinterpret_cast<short4*>(Vto + ((size_t)bh * DH_ + col) * S_ + sb) =
        pack4(vv0[0], vv0[1], vv0[2], vv0[3]);
    *reinterpret_cast<short4*>(Vto + ((size_t)bh * DH_ + 16 + col) * S_ + sb) =
        pack4(vv1[0], vv1[1], vv1[2], vv1[3]);
}

// ---------------------------------------------------------------------------
// Kernel 2: fused attention v7 — register P, 32 Q-ROWS PER WAVE.
// K/V/mask-word loads are shared across the two q-tiles, so loads-per-MFMA
// halves vs v6 and each iteration carries 2x independent work to fill the
// latency holes that source-level prefetch couldn't (R7: compiler re-sank it).
//   qA rows q0+col, qB rows q0+16+col; per 32-key tile: 4 QK MFMA,
//   16 exp2, 2 pack8, 4 PV MFMA.
// grid = (S/128, B*H, parts), block = 256 (4 waves x 32 q-rows)
// ---------------------------------------------------------------------------
__global__ __launch_bounds__(256) void attn_kernel(
    const __hip_bfloat16* __restrict__ Q,     // [B*H][S][DH] (pre-scaled)
    const __hip_bfloat16* __restrict__ K,     // [B*H][S][DH] permuted tiles
    const __hip_bfloat16* __restrict__ Vt,    // [B*H][DH][S]
    const unsigned int* __restrict__ mbits,   // [B][S][S/32]
    __hip_bfloat16* __restrict__ Op0,         // [B][S][E] part-0 unnormalized
    __hip_bfloat16* __restrict__ Op1,         // [B][S][E] part-1 unnormalized
    float* __restrict__ lpart)                // [parts][B*H][S]
{
    const int bh   = blockIdx.y;
    const int b    = bh / H_;
    const int h    = bh - b * H_;
    const int part = blockIdx.z;
    const int nkey = S_ / gridDim.z;
    const int kbeg = part * nkey;
    const int wave = threadIdx.x >> 6;
    const int lane = threadIdx.x & 63;
    const int col  = lane & 15;
    const int quad = lane >> 4;
    const int q0   = blockIdx.x * 128 + wave * 32;

    const __hip_bfloat16* Qbh = Q  + (size_t)bh * S_ * DH_;
    const __hip_bfloat16* Kbh = K  + (size_t)bh * S_ * DH_;
    const __hip_bfloat16* Vbh = Vt + (size_t)bh * DH_ * S_;

    const short8 qA = *reinterpret_cast<const short8*>(
        Qbh + (size_t)(q0 + col) * DH_ + quad * 8);
    const short8 qB = *reinterpret_cast<const short8*>(
        Qbh + (size_t)(q0 + 16 + col) * DH_ + quad * 8);

    const __hip_bfloat16* Kp  = Kbh + (size_t)(kbeg + col) * DH_ + quad * 8;
    const __hip_bfloat16* Vp0 = Vbh + (size_t)col * S_ + kbeg + quad * 8;
    const __hip_bfloat16* Vp1 = Vbh + (size_t)(16 + col) * S_ + kbeg + quad * 8;
    const unsigned int*   mbb = mbits + (size_t)b * S_ * SW_;
    const unsigned int*   mpA = mbb + (size_t)(q0 + col) * SW_ + (kbeg >> 5);
    const unsigned int*   mpB = mbb + (size_t)(q0 + 16 + col) * SW_ + (kbeg >> 5);

    f32x4 oA0 = {0.f,0.f,0.f,0.f}, oA1 = {0.f,0.f,0.f,0.f};
    f32x4 oB0 = {0.f,0.f,0.f,0.f}, oB1 = {0.f,0.f,0.f,0.f};
    float lA = 0.f, lB = 0.f;

    const int niter = nkey >> 5;
    for (int it = 0; it < niter; ++it) {
        const unsigned int mwA = *mpA;
        const unsigned int mwB = *mpB;
        const short8 kf0 = *reinterpret_cast<const short8*>(Kp);            // slots 0-15
        const short8 kf1 = *reinterpret_cast<const short8*>(Kp + 16 * DH_); // slots 16-31
        const short8 vf0 = *reinterpret_cast<const short8*>(Vp0);
        const short8 vf1 = *reinterpret_cast<const short8*>(Vp1);

        const f32x4 z = {0.f, 0.f, 0.f, 0.f};
        const f32x4 sA0 = __builtin_amdgcn_mfma_f32_16x16x32_bf16(kf0, qA, z, 0, 0, 0);
        const f32x4 sA1 = __builtin_amdgcn_mfma_f32_16x16x32_bf16(kf1, qA, z, 0, 0, 0);
        const f32x4 sB0 = __builtin_amdgcn_mfma_f32_16x16x32_bf16(kf0, qB, z, 0, 0, 0);
        const f32x4 sB1 = __builtin_amdgcn_mfma_f32_16x16x32_bf16(kf1, qB, z, 0, 0, 0);

        float pA0[4], pA1[4], pB0[4], pB1[4];
#pragma unroll
        for (int r = 0; r < 4; ++r) {
            const int kb = quad * 8 + r;
            const float tA0 = ((mwA >> kb)       & 1u) ? sA0[r] : MLOG2E;
            const float tA1 = ((mwA >> (kb + 4)) & 1u) ? sA1[r] : MLOG2E;
            const float tB0 = ((mwB >> kb)       & 1u) ? sB0[r] : MLOG2E;
            const float tB1 = ((mwB >> (kb + 4)) & 1u) ? sB1[r] : MLOG2E;
            pA0[r] = __builtin_amdgcn_exp2f(tA0);
            pA1[r] = __builtin_amdgcn_exp2f(tA1);
            pB0[r] = __builtin_amdgcn_exp2f(tB0);
            pB1[r] = __builtin_amdgcn_exp2f(tB1);
        }
        lA += ((pA0[0] + pA0[1]) + (pA0[2] + pA0[3]))
            + ((pA1[0] + pA1[1]) + (pA1[2] + pA1[3]));
        lB += ((pB0[0] + pB0[1]) + (pB0[2] + pB0[3]))
            + ((pB1[0] + pB1[1]) + (pB1[2] + pB1[3]));

        const short8 pfA = pack8f(pA0, pA1);
        const short8 pfB = pack8f(pB0, pB1);

        oA0 = __builtin_amdgcn_mfma_f32_16x16x32_bf16(vf0, pfA, oA0, 0, 0, 0);
        oA1 = __builtin_amdgcn_mfma_f32_16x16x32_bf16(vf1, pfA, oA1, 0, 0, 0);
        oB0 = __builtin_amdgcn_mfma_f32_16x16x32_bf16(vf0, pfB, oB0, 0, 0, 0);
        oB1 = __builtin_amdgcn_mfma_f32_16x16x32_bf16(vf1, pfB, oB1, 0, 0, 0);

        Kp  += 32 * DH_;
        Vp0 += 32;
        Vp1 += 32;
        mpA += 1;
        mpB += 1;
    }

    lA += __shfl_xor(lA, 16);
    lA += __shfl_xor(lA, 32);
    lB += __shfl_xor(lB, 16);
    lB += __shfl_xor(lB, 32);

    __hip_bfloat16* Ob = part ? Op1 : Op0;
    __hip_bfloat16* orowA = Ob + ((size_t)b * S_ + q0 + col) * E_ + h * DH_;
    __hip_bfloat16* orowB = Ob + ((size_t)b * S_ + q0 + 16 + col) * E_ + h * DH_;
    *reinterpret_cast<short4*>(orowA + quad * 4)      = pack4(oA0[0], oA0[1], oA0[2], oA0[3]);
    *reinterpret_cast<short4*>(orowA + 16 + quad * 4) = pack4(oA1[0], oA1[1], oA1[2], oA1[3]);
    *reinterpret_cast<short4*>(orowB + quad * 4)      = pack4(oB0[0], oB0[1], oB0[2], oB0[3]);
    *reinterpret_cast<short4*>(orowB + 16 + quad * 4) = pack4(oB1[0], oB1[1], oB1[2], oB1[3]);
    if (quad == 0) {
        float* lp = lpart + (size_t)part * B_ * H_ * S_ + (size_t)bh * S_;
        lp[q0 + col]      = lA;
        lp[q0 + 16 + col] = lB;
    }
}

// ---------------------------------------------------------------------------
// Kernel 3: output projection FUSED with split-K combine. A-fragments are
// normalized on the fly: a = (O0 + O1) * 1/(l0 + l1). Each 32-wide k-chunk
// lies within one head, so one l per lane per part per k-iter.
// Wave: 16 m x 64 n. grid = (M/16, 768/256), block = 256.
// ---------------------------------------------------------------------------
__global__ __launch_bounds__(256) void proj_kernel(
    const __hip_bfloat16* __restrict__ Op0,   // [4096][768] bf16
    const __hip_bfloat16* __restrict__ Op1,   // [4096][768] bf16 (parts==2)
    const float* __restrict__ lpart,          // [parts][B*H][S]
    const __hip_bfloat16* __restrict__ Wob,   // [768][768] bf16
    const float* __restrict__ bo,             // [768] fp32
    float* __restrict__ out,                  // [4096][768] fp32
    int parts)
{
    const int wave = threadIdx.x >> 6;
    const int lane = threadIdx.x & 63;
    const int col  = lane & 15;
    const int quad = lane >> 4;
    const int m0   = blockIdx.x * 16;
    const int n0   = blockIdx.y * 256 + wave * 64;

    const int m = m0 + col;
    const int b = m / S_;
    const int s = m - b * S_;
    const float* lp0 = lpart + (size_t)(b * H_) * S_ + s;
    const float* lp1 = lp0 + (size_t)B_ * H_ * S_;

    f32x4 acc[4] = {{0.f,0.f,0.f,0.f},{0.f,0.f,0.f,0.f},
                    {0.f,0.f,0.f,0.f},{0.f,0.f,0.f,0.f}};
    for (int k0 = 0; k0 < E_; k0 += 32) {
        const int h = k0 >> 5;
        const size_t aofs = (size_t)m * E_ + k0 + quad * 8;
        const short8 a0 = *reinterpret_cast<const short8*>(Op0 + aofs);
        float l = lp0[(size_t)h * S_];
        float av[8];
#pragma unroll
        for (int i = 0; i < 8; ++i) av[i] = bf16tof(a0[i]);
        if (parts == 2) {
            const short8 a1 = *reinterpret_cast<const short8*>(Op1 + aofs);
            l += lp1[(size_t)h * S_];
#pragma unroll
            for (int i = 0; i < 8; ++i) av[i] += bf16tof(a1[i]);
        }
        const float linv = 1.0f / l;
#pragma unroll
        for (int i = 0; i < 8; ++i) av[i] *= linv;
        const short8 af = pack8f(av, av + 4);

#pragma unroll
        for (int j = 0; j < 4; ++j) {
            const short8 bf = *reinterpret_cast<const short8*>(
                Wob + (size_t)(n0 + j * 16 + col) * E_ + k0 + quad * 8);
            acc[j] = __builtin_amdgcn_mfma_f32_16x16x32_bf16(af, bf, acc[j], 0, 0, 0);
        }
    }
#pragma unroll
    for (int j = 0; j < 4; ++j) {
        const int n = n0 + j * 16 + col;
        const float bias = bo[n];
#pragma unroll
        for (int r = 0; r < 4; ++r) {
            const int mm = m0 + quad * 4 + r;
            out[(size_t)mm * E_ + n] = acc[j][r] + bias;
        }
    }
}

// ---------------------------------------------------------------------------
extern "C" void kernel_launch(void* const* d_in, const int* in_sizes, int n_in,
                              void* d_out, int out_size, void* d_ws, size_t ws_size,
                              hipStream_t stream)
{
    const float* emb = (const float*)d_in[0];
    const int*   msk = (const int*)d_in[1];
    const float* Wq  = (const float*)d_in[2];
    const float* Wk  = (const float*)d_in[3];
    const float* Wv  = (const float*)d_in[4];
    const float* Wo  = (const float*)d_in[5];
    const float* bo  = (const float*)d_in[6];
    float* out = (float*)d_out;

    const size_t nqkv = (size_t)B_ * H_ * S_ * DH_;   // 3,145,728 (= B*S*E)
    char* p = (char*)d_ws;
    __hip_bfloat16* Q    = (__hip_bfloat16*)p;  p += nqkv * 2;
    __hip_bfloat16* Kp   = (__hip_bfloat16*)p;  p += nqkv * 2;
    __hip_bfloat16* Vt   = (__hip_bfloat16*)p;  p += nqkv * 2;
    __hip_bfloat16* Op0  = (__hip_bfloat16*)p;  p += nqkv * 2;   // old att slot
    unsigned int*  mbits = (unsigned int*)p;    p += (size_t)B_ * S_ * SW_ * 4;
    __hip_bfloat16* Wob  = (__hip_bfloat16*)p;  p += (size_t)E_ * E_ * 2;
    __hip_bfloat16* WTq  = (__hip_bfloat16*)p;  p += (size_t)H_ * DH_ * DH_ * 2;
    __hip_bfloat16* WTk  = (__hip_bfloat16*)p;  p += (size_t)H_ * DH_ * DH_ * 2;
    __hip_bfloat16* WTv  = (__hip_bfloat16*)p;  p += (size_t)H_ * DH_ * DH_ * 2;
    __hip_bfloat16* Op1  = (__hip_bfloat16*)p;  p += nqkv * 2;
    float*          lpart= (float*)p;           p += (size_t)2 * B_ * H_ * S_ * 4;
    // total ~34.6 MB; parts=2 already proven to fit (R4 ran with need=40.1MB)

    int parts = (ws_size >= (size_t)(p - (char*)d_ws)) ? 2 : 1;
    if (parts == 1) { Op1 = Op0; }

    prep_kernel<<<NB_MASK + NB_WO + NB_WT, 256, 0, stream>>>(
        msk, Wo, Wq, Wk, Wv, mbits, Wob, WTq, WTk, WTv);
    qkv_kernel <<<dim3(S_ / 64, B_ * H_), 256, 0, stream>>>(
        emb, WTq, WTk, WTv, Q, Kp, Vt);
    attn_kernel<<<dim3(S_ / 128, B_ * H_, parts), 256, 0, stream>>>(
        Q, Kp, Vt, mbits, Op0, Op1, lpart);
    proj_kernel<<<dim3((B_ * S_) / 16, E_ / 256), 256, 0, stream>>>(
        Op0, Op1, lpart, Wob, bo, out, parts);
}